// Round 1
// baseline (4728.611 us; speedup 1.0000x reference)
//
#include <hip/hip_runtime.h>
#include <cstdint>
#include <cstddef>

#define D_ 512
#define S_ 25
#define H_ 16
#define HD_ 32
#define DEPTH_ 3
#define NG_ 250
#define BATCH_ 4096
#define M_ (BATCH_ * S_) /* 102400 */
#define EPS_ 1e-5f

typedef __attribute__((ext_vector_type(8))) short short8;
typedef __attribute__((ext_vector_type(4))) short short4v;
typedef __attribute__((ext_vector_type(4))) float f32x4;

__device__ __forceinline__ float b2f(short s) {
  union { unsigned u; float f; } c;
  c.u = ((unsigned)(unsigned short)s) << 16;
  return c.f;
}
__device__ __forceinline__ short f2b(float f) {
  union { float f; unsigned u; } c; c.f = f;
  unsigned u = c.u + 0x7FFFu + ((c.u >> 16) & 1u);
  return (short)(u >> 16);
}

__device__ __forceinline__ void gld_lds16(const void* g, void* l) {
  __builtin_amdgcn_global_load_lds((const __attribute__((address_space(1))) void*)g,
                                   (__attribute__((address_space(3))) void*)l, 16, 0, 0);
}

// ---------------------------------------------------------------------------
// f32 -> bf16 conversion (weights), 4 elems/thread
// ---------------------------------------------------------------------------
__global__ __launch_bounds__(256) void cvt_f2b_ker(const float* __restrict__ in,
                                                   short* __restrict__ out, int n4) {
  int i = blockIdx.x * 256 + threadIdx.x;
  if (i < n4) {
    f32x4 v = *(const f32x4*)(in + (size_t)i * 4);
    short4v o;
#pragma unroll
    for (int j = 0; j < 4; ++j) o[j] = f2b(v[j]);
    *(short4v*)(out + (size_t)i * 4) = o;
  }
}

// ---------------------------------------------------------------------------
// LayerNorm: one wave per 512-row. bf16 output variant (for GEMM A input).
// ---------------------------------------------------------------------------
__global__ __launch_bounds__(256) void ln_to_bf16_ker(const float* __restrict__ x,
                                                      const float* __restrict__ g,
                                                      const float* __restrict__ bb,
                                                      short* __restrict__ out) {
  int row = (blockIdx.x << 2) + (threadIdx.x >> 6);
  int l = threadIdx.x & 63;
  const float* xr = x + (size_t)row * D_ + l * 8;
  f32x4 a = *(const f32x4*)xr;
  f32x4 b2v = *(const f32x4*)(xr + 4);
  float v[8];
#pragma unroll
  for (int j = 0; j < 4; ++j) { v[j] = a[j]; v[j + 4] = b2v[j]; }
  float s = 0.f, q = 0.f;
#pragma unroll
  for (int j = 0; j < 8; ++j) { s += v[j]; q += v[j] * v[j]; }
#pragma unroll
  for (int off = 32; off; off >>= 1) { s += __shfl_xor(s, off); q += __shfl_xor(q, off); }
  float mean = s * (1.0f / 512.0f);
  float var = q * (1.0f / 512.0f) - mean * mean;
  float rstd = rsqrtf(var + EPS_);
  const float* gp = g + l * 8;
  const float* bp = bb + l * 8;
  f32x4 g0 = *(const f32x4*)gp, g1 = *(const f32x4*)(gp + 4);
  f32x4 b0 = *(const f32x4*)bp, b1 = *(const f32x4*)(bp + 4);
  short8 o;
#pragma unroll
  for (int j = 0; j < 8; ++j) {
    float gg = (j < 4) ? g0[j] : g1[j - 4];
    float bv = (j < 4) ? b0[j] : b1[j - 4];
    o[j] = f2b((v[j] - mean) * rstd * gg + bv);
  }
  *(short8*)(out + (size_t)row * D_ + l * 8) = o;
}

// f32 in-place variant (final LN on d_out x region)
__global__ __launch_bounds__(256) void ln_f32_inplace_ker(float* __restrict__ x,
                                                          const float* __restrict__ g,
                                                          const float* __restrict__ bb) {
  int row = (blockIdx.x << 2) + (threadIdx.x >> 6);
  int l = threadIdx.x & 63;
  float* xr = x + (size_t)row * D_ + l * 8;
  f32x4 a = *(const f32x4*)xr;
  f32x4 b2v = *(const f32x4*)(xr + 4);
  float v[8];
#pragma unroll
  for (int j = 0; j < 4; ++j) { v[j] = a[j]; v[j + 4] = b2v[j]; }
  float s = 0.f, q = 0.f;
#pragma unroll
  for (int j = 0; j < 8; ++j) { s += v[j]; q += v[j] * v[j]; }
#pragma unroll
  for (int off = 32; off; off >>= 1) { s += __shfl_xor(s, off); q += __shfl_xor(q, off); }
  float mean = s * (1.0f / 512.0f);
  float var = q * (1.0f / 512.0f) - mean * mean;
  float rstd = rsqrtf(var + EPS_);
  const float* gp = g + l * 8;
  const float* bp = bb + l * 8;
  f32x4 g0 = *(const f32x4*)gp, g1 = *(const f32x4*)(gp + 4);
  f32x4 b0 = *(const f32x4*)bp, b1 = *(const f32x4*)(bp + 4);
  f32x4 o0, o1;
#pragma unroll
  for (int j = 0; j < 4; ++j) {
    o0[j] = (v[j] - mean) * rstd * g0[j] + b0[j];
    o1[j] = (v[j + 4] - mean) * rstd * g1[j] + b1[j];
  }
  *(f32x4*)xr = o0;
  *(f32x4*)(xr + 4) = o1;
}

// ---------------------------------------------------------------------------
// bf16 GEMM: out[m][n] = sum_k A[m][k] * W[n][k] + bias[n]   (K = 512 fixed)
// 128x128 tile, BK=64, 4 waves (2x2), mfma_f32_16x16x32_bf16, XOR-swizzled LDS,
// global_load_lds width-16 staging.
// EPI: 0 = store bf16, 1 = f32 residual add into Xres, 2 = exact GELU -> bf16
// ---------------------------------------------------------------------------
template <int EPI>
__global__ __launch_bounds__(256) void gemm_bf16_ker(const short* __restrict__ A,
                                                     const short* __restrict__ Bw,
                                                     const float* __restrict__ bias,
                                                     short* __restrict__ Obf,
                                                     float* __restrict__ Xres, int N) {
  constexpr int K = 512;
  __shared__ short At[128 * 64];
  __shared__ short Bt[128 * 64];
  const int tid = threadIdx.x;
  const int l = tid & 63;
  const int w = tid >> 6;
  const int wr = w >> 1, wc = w & 1;
  const int m0 = blockIdx.y * 128;
  const int n0 = blockIdx.x * 128;

  f32x4 acc[4][4] = {};

  for (int kt = 0; kt < K; kt += 64) {
#pragma unroll
    for (int i = 0; i < 4; ++i) {
      int chunk = i * 256 + tid;
      int row = chunk >> 3;
      int colS = ((chunk & 7) << 3) ^ ((row & 7) << 3);  // swizzled source col (shorts)
      const short* ga = A + (size_t)(m0 + row) * K + kt + colS;
      const short* gb = Bw + (size_t)(n0 + row) * K + kt + colS;
      int base = (i * 256 + (w << 6)) << 3;  // wave-uniform LDS base (shorts)
      gld_lds16(ga, &At[base]);
      gld_lds16(gb, &Bt[base]);
    }
    __syncthreads();
#pragma unroll
    for (int kk = 0; kk < 64; kk += 32) {
      short8 af[4], bfr[4];
#pragma unroll
      for (int mi = 0; mi < 4; ++mi) {
        int row = (wr << 6) + (mi << 4) + (l & 15);
        int colS = (kk + ((l >> 4) << 3)) ^ ((row & 7) << 3);
        af[mi] = *(const short8*)&At[row * 64 + colS];
      }
#pragma unroll
      for (int ni = 0; ni < 4; ++ni) {
        int row = (wc << 6) + (ni << 4) + (l & 15);
        int colS = (kk + ((l >> 4) << 3)) ^ ((row & 7) << 3);
        bfr[ni] = *(const short8*)&Bt[row * 64 + colS];
      }
#pragma unroll
      for (int mi = 0; mi < 4; ++mi)
#pragma unroll
        for (int ni = 0; ni < 4; ++ni)
          acc[mi][ni] = __builtin_amdgcn_mfma_f32_16x16x32_bf16(af[mi], bfr[ni], acc[mi][ni], 0, 0, 0);
    }
    __syncthreads();
  }

  const int lrow = (l >> 4) << 2;  // +reg -> row within 16
  const int lcol = l & 15;
#pragma unroll
  for (int ni = 0; ni < 4; ++ni) {
    int gn = n0 + (wc << 6) + (ni << 4) + lcol;
    float bs = bias[gn];
#pragma unroll
    for (int mi = 0; mi < 4; ++mi) {
      int gm = m0 + (wr << 6) + (mi << 4) + lrow;
#pragma unroll
      for (int r = 0; r < 4; ++r) {
        float v = acc[mi][ni][r] + bs;
        size_t idx = (size_t)(gm + r) * N + gn;
        if (EPI == 0) {
          Obf[idx] = f2b(v);
        } else if (EPI == 1) {
          Xres[idx] += v;
        } else {
          Obf[idx] = f2b(0.5f * v * (1.0f + erff(v * 0.70710678118654752f)));
        }
      }
    }
  }
}

// ---------------------------------------------------------------------------
// Per-cell attention. qkv row layout [token][1536]: q[0:512], k[512:1024],
// v[1024:1536], channel c = h*32+d. One block per cell; K,V staged in LDS.
// ---------------------------------------------------------------------------
__global__ __launch_bounds__(512) void attn_ker(const short* __restrict__ qkv,
                                                const float* __restrict__ bias_table,
                                                short* __restrict__ o) {
  __shared__ short skv[S_ * 1024];  // [s][0:512]=k, [512:1024]=v  (51200 B)
  int b = blockIdx.x;
  const short* cell = qkv + (size_t)b * S_ * 1536;
  for (int idx = threadIdx.x; idx < S_ * 1024 / 8; idx += 512) {
    int srow = idx >> 7;          // idx / 128
    int c = (idx & 127) << 3;     // short offset within 1024
    *(short8*)(skv + srow * 1024 + c) = *(const short8*)(cell + (size_t)srow * 1536 + 512 + c);
  }
  __syncthreads();
  int t = threadIdx.x;
  if (t < H_ * S_) {
    int h = t / S_;
    int i = t - h * S_;
    // load q from global (L2-hot)
    const short* qp = cell + (size_t)i * 1536 + h * HD_;
    float q[HD_];
#pragma unroll
    for (int c = 0; c < 4; ++c) {
      short8 v = *(const short8*)(qp + c * 8);
#pragma unroll
      for (int jj = 0; jj < 8; ++jj) q[c * 8 + jj] = b2f(v[jj]);
    }
    const float scale = 0.17677669529663687f;  // 1/sqrt(32)
    int xi = i / 5, yi = i - xi * 5;
    float sc[S_];
    float mx = -1e30f;
#pragma unroll
    for (int j = 0; j < S_; ++j) {
      const short* kp = skv + j * 1024 + h * HD_;
      float s = 0.f;
#pragma unroll
      for (int c = 0; c < 4; ++c) {
        short8 v = *(const short8*)(kp + c * 8);
#pragma unroll
        for (int jj = 0; jj < 8; ++jj) s += q[c * 8 + jj] * b2f(v[jj]);
      }
      int xj = j / 5, yj = j - xj * 5;
      int ridx = (xi - xj + 4) * 9 + (yi - yj + 4);
      s = s * scale + bias_table[ridx * H_ + h];
      sc[j] = s;
      mx = fmaxf(mx, s);
    }
    float den = 0.f;
#pragma unroll
    for (int j = 0; j < S_; ++j) {
      float e = __expf(sc[j] - mx);
      sc[j] = e;
      den += e;
    }
    float inv = 1.0f / den;
    float ov[HD_];
#pragma unroll
    for (int d = 0; d < HD_; ++d) ov[d] = 0.f;
#pragma unroll
    for (int j = 0; j < S_; ++j) {
      float pr = sc[j] * inv;
      const short* vp = skv + j * 1024 + 512 + h * HD_;
#pragma unroll
      for (int c = 0; c < 4; ++c) {
        short8 v = *(const short8*)(vp + c * 8);
#pragma unroll
        for (int jj = 0; jj < 8; ++jj) ov[c * 8 + jj] += pr * b2f(v[jj]);
      }
    }
    short* op = o + ((size_t)b * S_ + i) * D_ + h * HD_;
#pragma unroll
    for (int c = 0; c < 4; ++c) {
      short8 v;
#pragma unroll
      for (int jj = 0; jj < 8; ++jj) v[jj] = f2b(ov[c * 8 + jj]);
      *(short8*)(op + c * 8) = v;
    }
  }
}

// ---------------------------------------------------------------------------
// Mean-pool over S then pred head: pred[b][n] = pooled . pred_w[n] + pred_b[n]
// ---------------------------------------------------------------------------
__global__ __launch_bounds__(256) void pred_ker(const float* __restrict__ xf,
                                                const float* __restrict__ pw,
                                                const float* __restrict__ pb,
                                                float* __restrict__ pred) {
  __shared__ float pooled[D_];
  int b = blockIdx.x;
  const float* xb = xf + (size_t)b * S_ * D_;
  for (int d = threadIdx.x; d < D_; d += 256) {
    float s = 0.f;
#pragma unroll
    for (int j = 0; j < S_; ++j) s += xb[(size_t)j * D_ + d];
    pooled[d] = s * (1.0f / 25.0f);
  }
  __syncthreads();
  for (int n = threadIdx.x; n < NG_; n += 256) {
    const float* w = pw + (size_t)n * D_;
    float s = pb[n];
    for (int d = 0; d < D_; d += 4) {
      f32x4 wv = *(const f32x4*)(w + d);
      s += pooled[d] * wv[0] + pooled[d + 1] * wv[1] + pooled[d + 2] * wv[2] +
           pooled[d + 3] * wv[3];
    }
    pred[(size_t)b * NG_ + n] = s;
  }
}

// ---------------------------------------------------------------------------
extern "C" void kernel_launch(void* const* d_in, const int* in_sizes, int n_in,
                              void* d_out, int out_size, void* d_ws, size_t ws_size,
                              hipStream_t stream) {
  const float* nf = (const float*)d_in[0];
  const float* bias_table = (const float*)d_in[1];
  const float* ln1_g = (const float*)d_in[2];
  const float* ln1_b = (const float*)d_in[3];
  const float* wqkv = (const float*)d_in[4];
  const float* bqkv = (const float*)d_in[5];
  const float* wo = (const float*)d_in[6];
  const float* bo = (const float*)d_in[7];
  const float* ln2_g = (const float*)d_in[8];
  const float* ln2_b = (const float*)d_in[9];
  const float* w1 = (const float*)d_in[10];
  const float* b1 = (const float*)d_in[11];
  const float* w2 = (const float*)d_in[12];
  const float* b2 = (const float*)d_in[13];
  const float* lnf_g = (const float*)d_in[14];
  const float* lnf_b = (const float*)d_in[15];
  const float* pred_w = (const float*)d_in[16];
  const float* pred_b = (const float*)d_in[17];

  float* x = (float*)d_out;                 // residual stream lives in d_out x-region
  float* pred = x + (size_t)M_ * D_;        // [4096][250]

  char* p = (char*)d_ws;
  short* qkvb = (short*)p; p += (size_t)M_ * 1536 * 2;
  short* xnb = (short*)p;  p += (size_t)M_ * D_ * 2;
  short* ob = (short*)p;   p += (size_t)M_ * D_ * 2;
  short* hb = (short*)p;   p += (size_t)M_ * D_ * 2;
  short* wqkvb = (short*)p; p += (size_t)DEPTH_ * 1536 * 512 * 2;
  short* wob = (short*)p;   p += (size_t)DEPTH_ * 512 * 512 * 2;
  short* w1b = (short*)p;   p += (size_t)DEPTH_ * 512 * 512 * 2;
  short* w2b = (short*)p;   p += (size_t)DEPTH_ * 512 * 512 * 2;

  // x = neighbor_feats
  hipMemcpyAsync(x, nf, (size_t)M_ * D_ * sizeof(float), hipMemcpyDeviceToDevice, stream);

  // weights -> bf16
  {
    int n4 = DEPTH_ * 1536 * 512 / 4;
    cvt_f2b_ker<<<(n4 + 255) / 256, 256, 0, stream>>>(wqkv, wqkvb, n4);
    n4 = DEPTH_ * 512 * 512 / 4;
    cvt_f2b_ker<<<(n4 + 255) / 256, 256, 0, stream>>>(wo, wob, n4);
    cvt_f2b_ker<<<(n4 + 255) / 256, 256, 0, stream>>>(w1, w1b, n4);
    cvt_f2b_ker<<<(n4 + 255) / 256, 256, 0, stream>>>(w2, w2b, n4);
  }

  for (int L = 0; L < DEPTH_; ++L) {
    // LN1 -> xn (bf16)
    ln_to_bf16_ker<<<M_ / 4, 256, 0, stream>>>(x, ln1_g + L * D_, ln1_b + L * D_, xnb);
    // qkv = xn @ wqkv^T + bqkv (bf16 out)
    gemm_bf16_ker<0><<<dim3(1536 / 128, M_ / 128), 256, 0, stream>>>(
        xnb, wqkvb + (size_t)L * 1536 * 512, bqkv + (size_t)L * 1536, qkvb, nullptr, 1536);
    // attention -> o (bf16)
    attn_ker<<<BATCH_, 512, 0, stream>>>(qkvb, bias_table, ob);
    // x += o @ wo^T + bo
    gemm_bf16_ker<1><<<dim3(512 / 128, M_ / 128), 256, 0, stream>>>(
        ob, wob + (size_t)L * 512 * 512, bo + (size_t)L * D_, nullptr, x, 512);
    // LN2 -> xn
    ln_to_bf16_ker<<<M_ / 4, 256, 0, stream>>>(x, ln2_g + L * D_, ln2_b + L * D_, xnb);
    // h = gelu(xn @ w1^T + b1) (bf16 out)
    gemm_bf16_ker<2><<<dim3(512 / 128, M_ / 128), 256, 0, stream>>>(
        xnb, w1b + (size_t)L * 512 * 512, b1 + (size_t)L * D_, hb, nullptr, 512);
    // x += h @ w2^T + b2
    gemm_bf16_ker<1><<<dim3(512 / 128, M_ / 128), 256, 0, stream>>>(
        hb, w2b + (size_t)L * 512 * 512, b2 + (size_t)L * D_, nullptr, x, 512);
  }

  // final LN in place on d_out x region
  ln_f32_inplace_ker<<<M_ / 4, 256, 0, stream>>>(x, lnf_g, lnf_b);
  // pooled mean + pred head
  pred_ker<<<BATCH_, 256, 0, stream>>>(x, pred_w, pred_b, pred);
}